// Round 4
// baseline (685.960 us; speedup 1.0000x reference)
//
#include <hip/hip_runtime.h>
#include <stdint.h>

// bf16 carried as raw short; fragments per cdna_hip_programming.md §3
typedef short bf16x8 __attribute__((ext_vector_type(8)));
typedef float f32x4 __attribute__((ext_vector_type(4)));

#define ASYNC16(g, l) __builtin_amdgcn_global_load_lds( \
    (const __attribute__((address_space(1))) unsigned int*)(g), \
    (__attribute__((address_space(3))) unsigned int*)(l), 16, 0, 0)

__device__ __forceinline__ float bf2f(short u) {
  union { unsigned int i; float f; } v;
  v.i = ((unsigned int)(unsigned short)u) << 16;
  return v.f;
}
__device__ __forceinline__ short f2bf(float f) {
  union { float f; unsigned int i; } v;
  v.f = f;
  unsigned int r = (v.i + 0x7fffu + ((v.i >> 16) & 1u)) >> 16;
  return (short)(unsigned short)r;
}
// dtype-ambivalent scalar load: isbf ? bf16[i] : float[i]
__device__ __forceinline__ float ldf(const void* p, long i, int isbf) {
  return isbf ? bf2f(((const short*)p)[i]) : ((const float*)p)[i];
}

// ---------------------------------------------------------------------------
// Input dtype detection (proven discriminating: fp32 -> flag=0).
// ---------------------------------------------------------------------------
__global__ void detect_dtype(const short* __restrict__ x, int* __restrict__ flag) {
  if (threadIdx.x == 0 && blockIdx.x == 0) {
    int cnt = 0;
    for (int i = 0; i < 128; ++i) {
      int e = (((unsigned short)x[i]) >> 7) & 0xFF;
      if (e >= 110 && e <= 136) ++cnt;
    }
    *flag = (cnt >= 120) ? 1 : 0;
  }
}

// x -> xb (bf16), 8 elems/thread
__global__ __launch_bounds__(256) void convert_x(
    const void* __restrict__ xin, short* __restrict__ xb, const int* __restrict__ flag) {
  long i = (long)blockIdx.x * 2048 + (long)threadIdx.x * 8;
  if (*flag) {
    *(bf16x8*)(xb + i) = *(const bf16x8*)((const short*)xin + i);
  } else {
    const float* xf = (const float*)xin;
    short tmp[8];
    #pragma unroll
    for (int j = 0; j < 8; ++j) tmp[j] = f2bf(xf[i + j]);
    *(bf16x8*)(xb + i) = *(bf16x8*)tmp;
  }
}

// ---------------------------------------------------------------------------
// 2048x2048 transpose + dtype convert (weights), z selects matrix.
// ---------------------------------------------------------------------------
__global__ __launch_bounds__(256) void transpose_w(
    const void* __restrict__ S0, short* __restrict__ D0,
    const void* __restrict__ S1, short* __restrict__ D1,
    const void* __restrict__ S2, short* __restrict__ D2,
    const int* __restrict__ flag)
{
  int z = blockIdx.z;
  const void* S = (z == 0) ? S0 : (z == 1) ? S1 : S2;
  short* D = (z == 0) ? D0 : (z == 1) ? D1 : D2;
  int isbf = *flag;
  __shared__ short tile[32][33];
  int c0 = blockIdx.x * 32, r0 = blockIdx.y * 32;
  int tx = threadIdx.x, ty = threadIdx.y;
  #pragma unroll
  for (int i = 0; i < 4; ++i)
    tile[ty + 8*i][tx] = f2bf(ldf(S, (long)(r0 + ty + 8*i) * 2048 + c0 + tx, isbf));
  __syncthreads();
  #pragma unroll
  for (int i = 0; i < 4; ++i)
    D[(long)(c0 + ty + 8*i) * 2048 + r0 + tx] = tile[tx][ty + 8*i];
}

// ---------------------------------------------------------------------------
// V (b,t,h,d) -> Vt (b,h,d,t)
// ---------------------------------------------------------------------------
__global__ __launch_bounds__(256) void transpose_v(
    const short* __restrict__ Vr, short* __restrict__ Vt)
{
  __shared__ short tile[32][33];
  int bh = blockIdx.z;
  int b = bh >> 4, h = bh & 15;
  int t0 = blockIdx.x * 32, d0 = blockIdx.y * 32;
  int tx = threadIdx.x, ty = threadIdx.y;
  #pragma unroll
  for (int i = 0; i < 4; ++i)
    tile[ty + 8*i][tx] = Vr[(long)(b*2048 + t0 + ty + 8*i) * 2048 + h*128 + d0 + tx];
  __syncthreads();
  #pragma unroll
  for (int i = 0; i < 4; ++i)
    Vt[((long)bh * 128 + d0 + ty + 8*i) * 2048 + t0 + tx] = tile[tx][ty + 8*i];
}

// ---------------------------------------------------------------------------
// m97-style GEMM: C(MxN) = A(MxK) * Bt(NxK)^T, bf16 in, fp32 accum.
// 128x128 tile, BK=64, 4 waves, 4x4 16x16x32 MFMAs per wave.
// OutT = short (bf16) for intermediates, float for the final output.
// ---------------------------------------------------------------------------
template<typename OutT>
__global__ __launch_bounds__(256) void gemm_bt(
    const short* __restrict__ A,
    const short* __restrict__ B0, const short* __restrict__ B1, const short* __restrict__ B2,
    OutT* __restrict__ C0, OutT* __restrict__ C1, OutT* __restrict__ C2,
    int M, int N, int K)
{
  int z = blockIdx.z;
  const short* Bt = (z == 0) ? B0 : (z == 1) ? B1 : B2;
  OutT* C = (z == 0) ? C0 : (z == 1) ? C1 : C2;

  int m0 = blockIdx.y * 128, n0 = blockIdx.x * 128;
  int tid = threadIdx.x;
  int lane = tid & 63, w = tid >> 6;
  int quad = lane >> 4, l16 = lane & 15;
  int wm = w >> 1, wn = w & 1;

  __shared__ short As[128][64];
  __shared__ short Bs[128][64];

  f32x4 zero4 = {0.f, 0.f, 0.f, 0.f};
  f32x4 acc[4][4];
  #pragma unroll
  for (int i = 0; i < 4; ++i)
    #pragma unroll
    for (int j = 0; j < 4; ++j) acc[i][j] = zero4;

  int srow = w * 32 + (lane >> 3);   // staging row within tile
  int scol = (lane & 7) * 8;         // staging col (8 bf16 = 16B)

  for (int k0 = 0; k0 < K; k0 += 64) {
    #pragma unroll
    for (int i = 0; i < 4; ++i) {
      ASYNC16(A  + (long)(m0 + srow + i*8) * K + k0 + scol, &As[w*32 + i*8][0]);
      ASYNC16(Bt + (long)(n0 + srow + i*8) * K + k0 + scol, &Bs[w*32 + i*8][0]);
    }
    __syncthreads();
    #pragma unroll
    for (int kt = 0; kt < 2; ++kt) {
      bf16x8 af[4], bfr[4];
      #pragma unroll
      for (int i = 0; i < 4; ++i)
        af[i] = *(const bf16x8*)&As[wm*64 + i*16 + l16][kt*32 + quad*8];
      #pragma unroll
      for (int j = 0; j < 4; ++j)
        bfr[j] = *(const bf16x8*)&Bs[wn*64 + j*16 + l16][kt*32 + quad*8];
      #pragma unroll
      for (int i = 0; i < 4; ++i)
        #pragma unroll
        for (int j = 0; j < 4; ++j)
          acc[i][j] = __builtin_amdgcn_mfma_f32_16x16x32_bf16(af[i], bfr[j], acc[i][j], 0, 0, 0);
    }
    __syncthreads();
  }

  // epilogue: C/D layout col=lane&15, row=quad*4+reg  [m89-verified]
  #pragma unroll
  for (int i = 0; i < 4; ++i)
    #pragma unroll
    for (int j = 0; j < 4; ++j) {
      int row = m0 + wm*64 + i*16 + quad*4;
      int col = n0 + wn*64 + j*16 + l16;
      #pragma unroll
      for (int r = 0; r < 4; ++r) {
        float v = acc[i][j][r];
        if constexpr (sizeof(OutT) == 4)
          C[(long)(row + r) * N + col] = v;
        else
          C[(long)(row + r) * N + col] = (OutT)f2bf(v);
      }
    }
}

// ---------------------------------------------------------------------------
// Pointwise: gate (xb[:,:32] @ Wgate sigmoid) into V, RoPE+RMSNorm on Q,K.
// ---------------------------------------------------------------------------
__global__ __launch_bounds__(256) void pointwise(
    const short* __restrict__ xb, const void* __restrict__ ve,
    const void* __restrict__ cosb, const void* __restrict__ sinb,
    const void* __restrict__ Wg, const int* __restrict__ flag,
    short* __restrict__ Qr, short* __restrict__ Kr, short* __restrict__ Vr)
{
  int row = blockIdx.x;
  int tid = threadIdx.x;
  int isbf = *flag;
  __shared__ float xg[32];
  __shared__ float gates[16];
  if (tid < 32) xg[tid] = bf2f(xb[(long)row * 2048 + tid]);
  __syncthreads();
  if (tid < 16) {
    float g = 0.f;
    #pragma unroll
    for (int i = 0; i < 32; ++i) g += xg[i] * ldf(Wg, i*16 + tid, isbf);
    gates[tid] = 2.0f / (1.0f + __expf(-g));
  }
  __syncthreads();
  #pragma unroll
  for (int it = 0; it < 8; ++it) {
    int idx = it * 256 + tid;
    int h = idx >> 7;
    long p = (long)row * 2048 + idx;
    Vr[p] = f2bf(bf2f(Vr[p]) + gates[h] * ldf(ve, p, isbf));
  }
  int lane = tid & 63, w = tid >> 6;
  int t = row & 2047;
  #pragma unroll
  for (int it = 0; it < 8; ++it) {
    int unit = it * 4 + w;               // 0..31: 16 Q heads then 16 K heads
    short* P = (unit < 16) ? Qr : Kr;
    int h = unit & 15;
    long base = (long)row * 2048 + h * 128;
    float x1 = bf2f(P[base + lane]);
    float x2 = bf2f(P[base + lane + 64]);
    float c = ldf(cosb, t*64 + lane, isbf);
    float s = ldf(sinb, t*64 + lane, isbf);
    float r1 = x1 * c + x2 * s;
    float r2 = -x1 * s + x2 * c;
    float ss = r1*r1 + r2*r2;
    #pragma unroll
    for (int off = 32; off; off >>= 1) ss += __shfl_xor(ss, off);
    float rn = rsqrtf(ss * (1.0f/128.0f) + 1e-6f);
    P[base + lane]      = f2bf(r1 * rn);
    P[base + lane + 64] = f2bf(r2 * rn);
  }
}

// ---------------------------------------------------------------------------
// Flash attention: BQ=BK=64, 4 waves x 16 q-rows, HD=128.
// ---------------------------------------------------------------------------
#define ATT_SCALE 0.08838834764831845f
#define NEG_BIG  -1.0e30f

__global__ __launch_bounds__(256) void flash(
    const short* __restrict__ Q, const short* __restrict__ K,
    const short* __restrict__ Vt, short* __restrict__ Y)
{
  int qt = blockIdx.x;
  int bh = blockIdx.y;
  int b = bh >> 4, h = bh & 15;
  int q0 = qt * 64;
  int tid = threadIdx.x;
  int lane = tid & 63, w = tid >> 6;
  int quad = lane >> 4, l16 = lane & 15;

  __shared__ short Ks[64][128];
  __shared__ short Vts[128][64];
  __shared__ short Ps[4][16][64];

  // Q fragments in registers: A[m=lane&15][k=quad*8+j]
  int qrow = q0 + w*16 + l16;
  const short* Qb = Q + (long)(b*2048 + qrow) * 2048 + h*128;
  bf16x8 qf[4];
  #pragma unroll
  for (int kt = 0; kt < 4; ++kt)
    qf[kt] = *(const bf16x8*)(Qb + kt*32 + quad*8);

  f32x4 zero4 = {0.f, 0.f, 0.f, 0.f};
  f32x4 o[8];
  #pragma unroll
  for (int c = 0; c < 8; ++c) o[c] = zero4;
  float m_i[4], l_i[4];
  #pragma unroll
  for (int r = 0; r < 4; ++r) { m_i[r] = NEG_BIG; l_i[r] = 0.f; }

  int nt = qt + 1;
  for (int t = 0; t < nt; ++t) {
    int kv0 = t * 64;
    #pragma unroll
    for (int i = 0; i < 4; ++i) {
      int o1 = i*256 + tid;
      int key = o1 >> 4, doct = o1 & 15;
      ASYNC16(K + (long)(b*2048 + kv0 + key) * 2048 + h*128 + doct*8,
              ((short*)Ks) + (long)(i*256 + w*64) * 8);
      int d = o1 >> 3, koct = o1 & 7;
      ASYNC16(Vt + ((long)bh * 128 + d) * 2048 + kv0 + koct*8,
              ((short*)Vts) + (long)(i*256 + w*64) * 8);
    }
    __syncthreads();

    // S = Q K^T
    f32x4 s[4];
    #pragma unroll
    for (int c = 0; c < 4; ++c) {
      f32x4 acc = zero4;
      #pragma unroll
      for (int kt = 0; kt < 4; ++kt) {
        bf16x8 kf = *(const bf16x8*)&Ks[c*16 + l16][kt*32 + quad*8];
        acc = __builtin_amdgcn_mfma_f32_16x16x32_bf16(qf[kt], kf, acc, 0, 0, 0);
      }
      s[c] = acc;
    }

    // online softmax; rows owned per (quad, reg)
    float p[4][4];
    float mt[4];
    #pragma unroll
    for (int r = 0; r < 4; ++r) mt[r] = NEG_BIG;
    int qgb = q0 + w*16 + quad*4;
    #pragma unroll
    for (int c = 0; c < 4; ++c) {
      int kg = kv0 + c*16 + l16;
      #pragma unroll
      for (int r = 0; r < 4; ++r) {
        float v = s[c][r] * ATT_SCALE;
        v = (kg <= qgb + r) ? v : NEG_BIG;
        p[c][r] = v;
        mt[r] = fmaxf(mt[r], v);
      }
    }
    #pragma unroll
    for (int off = 1; off < 16; off <<= 1) {
      #pragma unroll
      for (int r = 0; r < 4; ++r) mt[r] = fmaxf(mt[r], __shfl_xor(mt[r], off));
    }
    float alpha[4], rs[4];
    #pragma unroll
    for (int r = 0; r < 4; ++r) {
      float mnew = fmaxf(m_i[r], mt[r]);
      alpha[r] = __expf(m_i[r] - mnew);
      m_i[r] = mnew;
      float sum = 0.f;
      #pragma unroll
      for (int c = 0; c < 4; ++c) { p[c][r] = __expf(p[c][r] - mnew); sum += p[c][r]; }
      rs[r] = sum;
    }
    #pragma unroll
    for (int off = 1; off < 16; off <<= 1) {
      #pragma unroll
      for (int r = 0; r < 4; ++r) rs[r] += __shfl_xor(rs[r], off);
    }
    #pragma unroll
    for (int r = 0; r < 4; ++r) l_i[r] = l_i[r] * alpha[r] + rs[r];
    #pragma unroll
    for (int c8 = 0; c8 < 8; ++c8)
      #pragma unroll
      for (int r = 0; r < 4; ++r) o[c8][r] *= alpha[r];

    // P: C-layout -> LDS -> A-layout
    #pragma unroll
    for (int c = 0; c < 4; ++c)
      #pragma unroll
      for (int r = 0; r < 4; ++r)
        Ps[w][quad*4 + r][c*16 + l16] = f2bf(p[c][r]);
    __syncthreads();
    bf16x8 pa0 = *(const bf16x8*)&Ps[w][l16][quad*8];
    bf16x8 pa1 = *(const bf16x8*)&Ps[w][l16][32 + quad*8];
    #pragma unroll
    for (int c8 = 0; c8 < 8; ++c8) {
      bf16x8 v0 = *(const bf16x8*)&Vts[c8*16 + l16][quad*8];
      bf16x8 v1 = *(const bf16x8*)&Vts[c8*16 + l16][32 + quad*8];
      o[c8] = __builtin_amdgcn_mfma_f32_16x16x32_bf16(pa0, v0, o[c8], 0, 0, 0);
      o[c8] = __builtin_amdgcn_mfma_f32_16x16x32_bf16(pa1, v1, o[c8], 0, 0, 0);
    }
    __syncthreads();
  }

  // epilogue: O /= l
  #pragma unroll
  for (int r = 0; r < 4; ++r) {
    float inv = 1.0f / fmaxf(l_i[r], 1e-20f);
    int qg = q0 + w*16 + quad*4 + r;
    short* yp = Y + (long)(b*2048 + qg) * 2048 + h*128;
    #pragma unroll
    for (int c8 = 0; c8 < 8; ++c8)
      yp[c8*16 + l16] = f2bf(o[c8][r] * inv);
  }
}

// ---------------------------------------------------------------------------
extern "C" void kernel_launch(void* const* d_in, const int* in_sizes, int n_in,
                              void* d_out, int out_size, void* d_ws, size_t ws_size,
                              hipStream_t stream) {
  const void* x    = d_in[0];
  const void* ve   = d_in[1];
  const void* cosb = d_in[2];
  const void* sinb = d_in[3];
  const void* Wq   = d_in[4];
  const void* Wk   = d_in[5];
  const void* Wv   = d_in[6];
  const void* Wg   = d_in[7];
  const void* Wp   = d_in[8];
  float* out = (float*)d_out;   // reference output dtype: float32

  int*   flag = (int*)d_ws;
  short* base = (short*)d_ws + 256;        // 512B header keeps 16B alignment
  short* wt0 = base;                       // 4M: Wq^T, then Wp^T
  short* wtk = base + 4194304L;            // 4M: Wk^T (dead after QKV gemm)
  short* wtv = base + 8388608L;            // 4M: Wv^T (dead after QKV gemm)
  short* Vt  = base + 4194304L;            // 8M: aliases wtk+wtv
  short* xb  = base + 12582912L;           // 8M: bf16 x (dead after pointwise)
  short* Y   = base + 12582912L;           // 8M: aliases xb
  short* Qr  = base + 20971520L;           // 8M
  short* Kr  = base + 29360128L;           // 8M
  short* Vr  = base + 37748736L;           // 8M   total ~88 MiB

  // 0. dtype detect + x conversion
  detect_dtype<<<1, 64, 0, stream>>>((const short*)x, flag);
  convert_x<<<4096, 256, 0, stream>>>(x, xb, flag);
  // 1. transpose (+convert) Wq, Wk, Wv
  transpose_w<<<dim3(64, 64, 3), dim3(32, 8), 0, stream>>>(Wq, wt0, Wk, wtk, Wv, wtv, flag);
  // 2. QKV projections (bf16 out)
  gemm_bt<short><<<dim3(16, 32, 3), 256, 0, stream>>>(xb, wt0, wtk, wtv, Qr, Kr, Vr, 4096, 2048, 2048);
  // 3. transpose (+convert) Wproj into wt0 (Wq^T dead)
  transpose_w<<<dim3(64, 64, 1), dim3(32, 8), 0, stream>>>(Wp, wt0, Wp, wt0, Wp, wt0, flag);
  // 4. gate + RoPE + RMSNorm (in place)
  pointwise<<<dim3(4096), 256, 0, stream>>>(xb, ve, cosb, sinb, Wg, flag, Qr, Kr, Vr);
  // 5. V -> Vt (b,h,d,t)  (Vt aliases dead wtk/wtv)
  transpose_v<<<dim3(64, 4, 32), dim3(32, 8), 0, stream>>>(Vr, Vt);
  // 6. flash attention (Y aliases dead xb)
  flash<<<dim3(32, 32), 256, 0, stream>>>(Qr, Kr, Vt, Y);
  // 7. output projection -> fp32 d_out
  gemm_bt<float><<<dim3(16, 32, 1), 256, 0, stream>>>(Y, wt0, wt0, wt0, out, out, out, 4096, 2048, 2048);
}

// Round 5
// 528.105 us; speedup vs baseline: 1.2989x; 1.2989x over previous
//
#include <hip/hip_runtime.h>
#include <stdint.h>

typedef short bf16x8 __attribute__((ext_vector_type(8)));
typedef float f32x4 __attribute__((ext_vector_type(4)));

#define ASYNC16(g, l) __builtin_amdgcn_global_load_lds( \
    (const __attribute__((address_space(1))) unsigned int*)(g), \
    (__attribute__((address_space(3))) unsigned int*)(l), 16, 0, 0)

__device__ __forceinline__ float bf2f(short u) {
  union { unsigned int i; float f; } v;
  v.i = ((unsigned int)(unsigned short)u) << 16;
  return v.f;
}
__device__ __forceinline__ short f2bf(float f) {
  union { float f; unsigned int i; } v;
  v.f = f;
  return (short)(unsigned short)((v.i + 0x8000u) >> 16);
}
__device__ __forceinline__ float ldf(const void* p, long i, int isbf) {
  return isbf ? bf2f(((const short*)p)[i]) : ((const float*)p)[i];
}

// ---------------------------------------------------------------------------
__global__ void detect_dtype(const short* __restrict__ x, int* __restrict__ flag) {
  if (threadIdx.x == 0 && blockIdx.x == 0) {
    int cnt = 0;
    for (int i = 0; i < 128; ++i) {
      int e = (((unsigned short)x[i]) >> 7) & 0xFF;
      if (e >= 110 && e <= 136) ++cnt;
    }
    *flag = (cnt >= 120) ? 1 : 0;
  }
}

__global__ __launch_bounds__(256) void convert_x(
    const void* __restrict__ xin, short* __restrict__ xb, const int* __restrict__ flag) {
  long i = (long)blockIdx.x * 2048 + (long)threadIdx.x * 8;
  if (*flag) {
    *(bf16x8*)(xb + i) = *(const bf16x8*)((const short*)xin + i);
  } else {
    const float* xf = (const float*)xin;
    short tmp[8];
    #pragma unroll
    for (int j = 0; j < 8; ++j) tmp[j] = f2bf(xf[i + j]);
    *(bf16x8*)(xb + i) = *(bf16x8*)tmp;
  }
}

// ---------------------------------------------------------------------------
__global__ __launch_bounds__(256) void transpose_w(
    const void* __restrict__ S0, short* __restrict__ D0,
    const void* __restrict__ S1, short* __restrict__ D1,
    const void* __restrict__ S2, short* __restrict__ D2,
    const int* __restrict__ flag)
{
  int z = blockIdx.z;
  const void* S = (z == 0) ? S0 : (z == 1) ? S1 : S2;
  short* D = (z == 0) ? D0 : (z == 1) ? D1 : D2;
  int isbf = *flag;
  __shared__ short tile[32][33];
  int c0 = blockIdx.x * 32, r0 = blockIdx.y * 32;
  int tx = threadIdx.x, ty = threadIdx.y;
  #pragma unroll
  for (int i = 0; i < 4; ++i)
    tile[ty + 8*i][tx] = f2bf(ldf(S, (long)(r0 + ty + 8*i) * 2048 + c0 + tx, isbf));
  __syncthreads();
  #pragma unroll
  for (int i = 0; i < 4; ++i)
    D[(long)(c0 + ty + 8*i) * 2048 + r0 + tx] = tile[tx][ty + 8*i];
}

__global__ __launch_bounds__(256) void transpose_v(
    const short* __restrict__ Vr, short* __restrict__ Vt)
{
  __shared__ short tile[32][33];
  int bh = blockIdx.z;
  int b = bh >> 4, h = bh & 15;
  int t0 = blockIdx.x * 32, d0 = blockIdx.y * 32;
  int tx = threadIdx.x, ty = threadIdx.y;
  #pragma unroll
  for (int i = 0; i < 4; ++i)
    tile[ty + 8*i][tx] = Vr[(long)(b*2048 + t0 + ty + 8*i) * 2048 + h*128 + d0 + tx];
  __syncthreads();
  #pragma unroll
  for (int i = 0; i < 4; ++i)
    Vt[((long)bh * 128 + d0 + ty + 8*i) * 2048 + t0 + tx] = tile[tx][ty + 8*i];
}

// ---------------------------------------------------------------------------
// GEMM with XOR-octet-swizzled LDS (kills the 2x bank aliasing m98 measured).
// Swizzle: data for (row, logical-octet lo) stored at physical octet
// po = lo ^ (row & 7). Staging via ASYNC16: lo = (lane&7) ^ (lane>>3).
// ---------------------------------------------------------------------------
template<typename OutT>
__global__ __launch_bounds__(256) void gemm_bt(
    const short* __restrict__ A,
    const short* __restrict__ B0, const short* __restrict__ B1, const short* __restrict__ B2,
    OutT* __restrict__ C0, OutT* __restrict__ C1, OutT* __restrict__ C2,
    int M, int N, int K)
{
  int z = blockIdx.z;
  const short* Bt = (z == 0) ? B0 : (z == 1) ? B1 : B2;
  OutT* C = (z == 0) ? C0 : (z == 1) ? C1 : C2;

  int m0 = blockIdx.y * 128, n0 = blockIdx.x * 128;
  int tid = threadIdx.x;
  int lane = tid & 63, w = tid >> 6;
  int quad = lane >> 4, l16 = lane & 15;
  int wm = w >> 1, wn = w & 1;

  __shared__ short As[128][64];
  __shared__ short Bs[128][64];

  f32x4 zero4 = {0.f, 0.f, 0.f, 0.f};
  f32x4 acc[4][4];
  #pragma unroll
  for (int i = 0; i < 4; ++i)
    #pragma unroll
    for (int j = 0; j < 4; ++j) acc[i][j] = zero4;

  int r8 = lane >> 3;
  int srow = w * 32 + r8;
  int scol = ((lane & 7) ^ r8) * 8;      // swizzled global octet

  for (int k0 = 0; k0 < K; k0 += 64) {
    #pragma unroll
    for (int i = 0; i < 4; ++i) {
      ASYNC16(A  + (long)(m0 + srow + i*8) * K + k0 + scol, &As[w*32 + i*8][0]);
      ASYNC16(Bt + (long)(n0 + srow + i*8) * K + k0 + scol, &Bs[w*32 + i*8][0]);
    }
    __syncthreads();
    #pragma unroll
    for (int kt = 0; kt < 2; ++kt) {
      int po = ((kt*4 + quad) ^ (l16 & 7)) * 8;
      bf16x8 af[4], bfr[4];
      #pragma unroll
      for (int i = 0; i < 4; ++i)
        af[i] = *(const bf16x8*)&As[wm*64 + i*16 + l16][po];
      #pragma unroll
      for (int j = 0; j < 4; ++j)
        bfr[j] = *(const bf16x8*)&Bs[wn*64 + j*16 + l16][po];
      #pragma unroll
      for (int i = 0; i < 4; ++i)
        #pragma unroll
        for (int j = 0; j < 4; ++j)
          acc[i][j] = __builtin_amdgcn_mfma_f32_16x16x32_bf16(af[i], bfr[j], acc[i][j], 0, 0, 0);
    }
    __syncthreads();
  }

  #pragma unroll
  for (int i = 0; i < 4; ++i)
    #pragma unroll
    for (int j = 0; j < 4; ++j) {
      int row = m0 + wm*64 + i*16 + quad*4;
      int col = n0 + wn*64 + j*16 + l16;
      #pragma unroll
      for (int r = 0; r < 4; ++r) {
        float v = acc[i][j][r];
        if constexpr (sizeof(OutT) == 4)
          C[(long)(row + r) * N + col] = v;
        else
          C[(long)(row + r) * N + col] = (OutT)f2bf(v);
      }
    }
}

// ---------------------------------------------------------------------------
__global__ __launch_bounds__(256) void pointwise(
    const short* __restrict__ xb, const void* __restrict__ ve,
    const void* __restrict__ cosb, const void* __restrict__ sinb,
    const void* __restrict__ Wg, const int* __restrict__ flag,
    short* __restrict__ Qr, short* __restrict__ Kr, short* __restrict__ Vr)
{
  int row = blockIdx.x;
  int tid = threadIdx.x;
  int isbf = *flag;
  __shared__ float xg[32];
  __shared__ float gates[16];
  if (tid < 32) xg[tid] = bf2f(xb[(long)row * 2048 + tid]);
  __syncthreads();
  if (tid < 16) {
    float g = 0.f;
    #pragma unroll
    for (int i = 0; i < 32; ++i) g += xg[i] * ldf(Wg, i*16 + tid, isbf);
    gates[tid] = 2.0f / (1.0f + __expf(-g));
  }
  __syncthreads();
  #pragma unroll
  for (int it = 0; it < 8; ++it) {
    int idx = it * 256 + tid;
    int h = idx >> 7;
    long p = (long)row * 2048 + idx;
    Vr[p] = f2bf(bf2f(Vr[p]) + gates[h] * ldf(ve, p, isbf));
  }
  int lane = tid & 63, w = tid >> 6;
  int t = row & 2047;
  #pragma unroll
  for (int it = 0; it < 8; ++it) {
    int unit = it * 4 + w;
    short* P = (unit < 16) ? Qr : Kr;
    int h = unit & 15;
    long base = (long)row * 2048 + h * 128;
    float x1 = bf2f(P[base + lane]);
    float x2 = bf2f(P[base + lane + 64]);
    float c = ldf(cosb, t*64 + lane, isbf);
    float s = ldf(sinb, t*64 + lane, isbf);
    float r1 = x1 * c + x2 * s;
    float r2 = -x1 * s + x2 * c;
    float ss = r1*r1 + r2*r2;
    #pragma unroll
    for (int off = 32; off; off >>= 1) ss += __shfl_xor(ss, off);
    float rn = rsqrtf(ss * (1.0f/128.0f) + 1e-6f);
    P[base + lane]      = f2bf(r1 * rn);
    P[base + lane + 64] = f2bf(r2 * rn);
  }
}

// ---------------------------------------------------------------------------
// Flash attention v2: BQ=64 (4 waves x 16 q-rows), BK=32, HD=128.
//  - paired q-tiles (bx, 31-bx): every block does exactly 66 tile-steps
//  - double-buffered K/V staging via ASYNC16, prefetch overlaps compute
//  - one raw s_barrier + per-wave vmcnt(0) per step
//  - XOR-octet swizzle on Ks/Vts (optimal 8 dwords/bank); Ps padded stride 40
// ---------------------------------------------------------------------------
#define ATT_SCALE 0.08838834764831845f
#define NEG_BIG  -1.0e30f

__global__ __launch_bounds__(256) void flash(
    const short* __restrict__ Q, const short* __restrict__ K,
    const short* __restrict__ Vt, short* __restrict__ Y)
{
  int bx = blockIdx.x;
  int bh = blockIdx.y;
  int b = bh >> 4, h = bh & 15;
  int tid = threadIdx.x;
  int lane = tid & 63, w = tid >> 6;
  int quad = lane >> 4, l16 = lane & 15;

  __shared__ short Ks[2][32*128];    // [key][16 octets], po = lo ^ (key&7)
  __shared__ short Vts[2][128*32];   // [dim][4 octets],  po = lo ^ (dim&3)
  __shared__ short Ps[4][16*40];     // wave-private, padded stride 40

  int qtA = bx, qtB = 31 - bx;
  int nA = 2*(qtA+1), nB = 2*(qtB+1);
  int total = nA + nB;

  // staging lane constants (swizzle folded into the global source octet)
  int kkey = tid >> 4;                       // + i*16
  int klo  = (tid & 15) ^ (kkey & 7);
  int vd   = tid >> 2;                       // + i*64
  int vlo  = (tid & 3) ^ (vd & 3);
  const short* Kb0 = K + (long)(b*2048 + kkey) * 2048 + h*128 + klo*8;
  const short* Kb1 = Kb0 + 16L*2048;
  const short* Vb0 = Vt + ((long)bh*128 + vd) * 2048 + vlo*8;
  const short* Vb1 = Vb0 + 64L*2048;

  f32x4 zero4 = {0.f, 0.f, 0.f, 0.f};
  f32x4 o[8];
  float m_i[4], l_i[4];
  bf16x8 qf[4];

  auto stage = [&](int tt, int buf) {
    int tl = (tt < nA) ? tt : tt - nA;
    long ko = (long)tl * 32 * 2048;
    int  vo = tl * 32;
    ASYNC16(Kb0 + ko, &Ks[buf][(w*64)*8]);
    ASYNC16(Kb1 + ko, &Ks[buf][(256 + w*64)*8]);
    ASYNC16(Vb0 + vo, &Vts[buf][(w*64)*8]);
    ASYNC16(Vb1 + vo, &Vts[buf][(256 + w*64)*8]);
  };
  auto loadQ = [&](int qt) {
    const short* Qb = Q + (long)(b*2048 + qt*64 + w*16 + l16) * 2048 + h*128;
    #pragma unroll
    for (int kt = 0; kt < 4; ++kt)
      qf[kt] = *(const bf16x8*)(Qb + kt*32 + quad*8);
  };
  auto flushO = [&](int qt) {
    #pragma unroll
    for (int r = 0; r < 4; ++r) {
      float inv = 1.0f / fmaxf(l_i[r], 1e-20f);
      short* yp = Y + (long)(b*2048 + qt*64 + w*16 + quad*4 + r) * 2048 + h*128;
      #pragma unroll
      for (int c8 = 0; c8 < 8; ++c8)
        yp[c8*16 + l16] = f2bf(o[c8][r] * inv);
    }
  };

  #pragma unroll
  for (int c = 0; c < 8; ++c) o[c] = zero4;
  #pragma unroll
  for (int r = 0; r < 4; ++r) { m_i[r] = NEG_BIG; l_i[r] = 0.f; }
  loadQ(qtA);
  stage(0, 0);

  int qt = qtA, n_seg = nA, segbase = 0;
  for (int tt = 0; tt < total; ++tt) {
    int buf = tt & 1;
    asm volatile("s_waitcnt vmcnt(0)" ::: "memory");
    __builtin_amdgcn_s_barrier();
    if (tt + 1 < total) stage(tt + 1, buf ^ 1);
    if (tt == nA) {                       // segment switch A -> B
      flushO(qtA);
      loadQ(qtB);
      #pragma unroll
      for (int c = 0; c < 8; ++c) o[c] = zero4;
      #pragma unroll
      for (int r = 0; r < 4; ++r) { m_i[r] = NEG_BIG; l_i[r] = 0.f; }
      qt = qtB; n_seg = nB; segbase = nA;
    }
    int tloc = tt - segbase;
    int kv0 = tloc * 32;

    // S = Q K^T  (16 q-rows x 32 keys per wave)
    f32x4 s[2];
    #pragma unroll
    for (int c = 0; c < 2; ++c) {
      f32x4 acc = zero4;
      #pragma unroll
      for (int kt = 0; kt < 4; ++kt) {
        int po = (kt*4 + quad) ^ (l16 & 7);
        bf16x8 kf = *(const bf16x8*)&Ks[buf][(c*16 + l16)*128 + po*8];
        acc = __builtin_amdgcn_mfma_f32_16x16x32_bf16(qf[kt], kf, acc, 0, 0, 0);
      }
      s[c] = acc;
    }

    // online softmax; mask only on the two diagonal tiles
    bool domask = (tloc >= n_seg - 2);
    float p[2][4], mt[4];
    #pragma unroll
    for (int r = 0; r < 4; ++r) mt[r] = NEG_BIG;
    int qgb = qt*64 + w*16 + quad*4;
    #pragma unroll
    for (int c = 0; c < 2; ++c) {
      int kg = kv0 + c*16 + l16;
      #pragma unroll
      for (int r = 0; r < 4; ++r) {
        float v = s[c][r] * ATT_SCALE;
        if (domask) v = (kg <= qgb + r) ? v : NEG_BIG;
        p[c][r] = v;
        mt[r] = fmaxf(mt[r], v);
      }
    }
    #pragma unroll
    for (int off = 1; off < 16; off <<= 1) {
      #pragma unroll
      for (int r = 0; r < 4; ++r) mt[r] = fmaxf(mt[r], __shfl_xor(mt[r], off));
    }
    float alpha[4], rs[4];
    #pragma unroll
    for (int r = 0; r < 4; ++r) {
      float mnew = fmaxf(m_i[r], mt[r]);
      alpha[r] = __expf(m_i[r] - mnew);
      m_i[r] = mnew;
      float sum = 0.f;
      #pragma unroll
      for (int c = 0; c < 2; ++c) { p[c][r] = __expf(p[c][r] - mnew); sum += p[c][r]; }
      rs[r] = sum;
    }
    #pragma unroll
    for (int off = 1; off < 16; off <<= 1) {
      #pragma unroll
      for (int r = 0; r < 4; ++r) rs[r] += __shfl_xor(rs[r], off);
    }
    #pragma unroll
    for (int r = 0; r < 4; ++r) l_i[r] = l_i[r] * alpha[r] + rs[r];
    #pragma unroll
    for (int c8 = 0; c8 < 8; ++c8)
      #pragma unroll
      for (int r = 0; r < 4; ++r) o[c8][r] *= alpha[r];

    // P: C-layout -> LDS (wave-private, padded) -> A-layout
    #pragma unroll
    for (int c = 0; c < 2; ++c)
      #pragma unroll
      for (int r = 0; r < 4; ++r)
        Ps[w][(quad*4 + r)*40 + c*16 + l16] = f2bf(p[c][r]);
    asm volatile("s_waitcnt lgkmcnt(0)" ::: "memory");
    bf16x8 pa = *(const bf16x8*)&Ps[w][l16*40 + quad*8];

    // O += P V
    int pov = quad ^ (l16 & 3);
    #pragma unroll
    for (int c8 = 0; c8 < 8; ++c8) {
      bf16x8 v0 = *(const bf16x8*)&Vts[buf][(c8*16 + l16)*32 + pov*8];
      o[c8] = __builtin_amdgcn_mfma_f32_16x16x32_bf16(pa, v0, o[c8], 0, 0, 0);
    }
  }
  flushO(qtB);
}

// ---------------------------------------------------------------------------
extern "C" void kernel_launch(void* const* d_in, const int* in_sizes, int n_in,
                              void* d_out, int out_size, void* d_ws, size_t ws_size,
                              hipStream_t stream) {
  const void* x    = d_in[0];
  const void* ve   = d_in[1];
  const void* cosb = d_in[2];
  const void* sinb = d_in[3];
  const void* Wq   = d_in[4];
  const void* Wk   = d_in[5];
  const void* Wv   = d_in[6];
  const void* Wg   = d_in[7];
  const void* Wp   = d_in[8];
  float* out = (float*)d_out;   // reference output dtype: float32

  int*   flag = (int*)d_ws;
  short* base = (short*)d_ws + 256;
  short* wt0 = base;                       // 4M: Wq^T, then Wp^T
  short* wtk = base + 4194304L;            // 4M: Wk^T (dead after QKV gemm)
  short* wtv = base + 8388608L;            // 4M: Wv^T (dead after QKV gemm)
  short* Vt  = base + 4194304L;            // 8M: aliases wtk+wtv
  short* xb  = base + 12582912L;           // 8M: bf16 x (dead after pointwise)
  short* Y   = base + 12582912L;           // 8M: aliases xb
  short* Qr  = base + 20971520L;           // 8M
  short* Kr  = base + 29360128L;           // 8M
  short* Vr  = base + 37748736L;           // 8M

  detect_dtype<<<1, 64, 0, stream>>>((const short*)x, flag);
  convert_x<<<4096, 256, 0, stream>>>(x, xb, flag);
  transpose_w<<<dim3(64, 64, 3), dim3(32, 8), 0, stream>>>(Wq, wt0, Wk, wtk, Wv, wtv, flag);
  gemm_bt<short><<<dim3(16, 32, 3), 256, 0, stream>>>(xb, wt0, wtk, wtv, Qr, Kr, Vr, 4096, 2048, 2048);
  transpose_w<<<dim3(64, 64, 1), dim3(32, 8), 0, stream>>>(Wp, wt0, Wp, wt0, Wp, wt0, flag);
  pointwise<<<dim3(4096), 256, 0, stream>>>(xb, ve, cosb, sinb, Wg, flag, Qr, Kr, Vr);
  transpose_v<<<dim3(64, 4, 32), dim3(32, 8), 0, stream>>>(Vr, Vt);
  flash<<<dim3(16, 32), 256, 0, stream>>>(Qr, Kr, Vt, Y);
  gemm_bt<float><<<dim3(16, 32, 1), 256, 0, stream>>>(Y, wt0, wt0, wt0, out, out, out, 4096, 2048, 2048);
}

// Round 6
// 477.389 us; speedup vs baseline: 1.4369x; 1.1062x over previous
//
#include <hip/hip_runtime.h>
#include <stdint.h>

typedef short bf16x8 __attribute__((ext_vector_type(8)));
typedef float f32x4 __attribute__((ext_vector_type(4)));

#define ASYNC16(g, l) __builtin_amdgcn_global_load_lds( \
    (const __attribute__((address_space(1))) unsigned int*)(g), \
    (__attribute__((address_space(3))) unsigned int*)(l), 16, 0, 0)

__device__ __forceinline__ float bf2f(short u) {
  union { unsigned int i; float f; } v;
  v.i = ((unsigned int)(unsigned short)u) << 16;
  return v.f;
}
__device__ __forceinline__ short f2bf(float f) {
  union { float f; unsigned int i; } v;
  v.f = f;
  return (short)(unsigned short)((v.i + 0x8000u) >> 16);
}
__device__ __forceinline__ float ldf(const void* p, long i, int isbf) {
  return isbf ? bf2f(((const short*)p)[i]) : ((const float*)p)[i];
}

// ---------------------------------------------------------------------------
__global__ void detect_dtype(const short* __restrict__ x, int* __restrict__ flag) {
  if (threadIdx.x == 0 && blockIdx.x == 0) {
    int cnt = 0;
    for (int i = 0; i < 128; ++i) {
      int e = (((unsigned short)x[i]) >> 7) & 0xFF;
      if (e >= 110 && e <= 136) ++cnt;
    }
    *flag = (cnt >= 120) ? 1 : 0;
  }
}

__global__ __launch_bounds__(256) void convert_x(
    const void* __restrict__ xin, short* __restrict__ xb, const int* __restrict__ flag) {
  long i = (long)blockIdx.x * 2048 + (long)threadIdx.x * 8;
  if (*flag) {
    *(bf16x8*)(xb + i) = *(const bf16x8*)((const short*)xin + i);
  } else {
    const float* xf = (const float*)xin;
    short tmp[8];
    #pragma unroll
    for (int j = 0; j < 8; ++j) tmp[j] = f2bf(xf[i + j]);
    *(bf16x8*)(xb + i) = *(bf16x8*)tmp;
  }
}

// ---------------------------------------------------------------------------
__global__ __launch_bounds__(256) void transpose_w(
    const void* __restrict__ S0, short* __restrict__ D0,
    const void* __restrict__ S1, short* __restrict__ D1,
    const void* __restrict__ S2, short* __restrict__ D2,
    const int* __restrict__ flag)
{
  int z = blockIdx.z;
  const void* S = (z == 0) ? S0 : (z == 1) ? S1 : S2;
  short* D = (z == 0) ? D0 : (z == 1) ? D1 : D2;
  int isbf = *flag;
  __shared__ short tile[32][33];
  int c0 = blockIdx.x * 32, r0 = blockIdx.y * 32;
  int tx = threadIdx.x, ty = threadIdx.y;
  #pragma unroll
  for (int i = 0; i < 4; ++i)
    tile[ty + 8*i][tx] = f2bf(ldf(S, (long)(r0 + ty + 8*i) * 2048 + c0 + tx, isbf));
  __syncthreads();
  #pragma unroll
  for (int i = 0; i < 4; ++i)
    D[(long)(c0 + ty + 8*i) * 2048 + r0 + tx] = tile[tx][ty + 8*i];
}

__global__ __launch_bounds__(256) void transpose_v(
    const short* __restrict__ Vr, short* __restrict__ Vt)
{
  __shared__ short tile[32][33];
  int bh = blockIdx.z;
  int b = bh >> 4, h = bh & 15;
  int t0 = blockIdx.x * 32, d0 = blockIdx.y * 32;
  int tx = threadIdx.x, ty = threadIdx.y;
  #pragma unroll
  for (int i = 0; i < 4; ++i)
    tile[ty + 8*i][tx] = Vr[(long)(b*2048 + t0 + ty + 8*i) * 2048 + h*128 + d0 + tx];
  __syncthreads();
  #pragma unroll
  for (int i = 0; i < 4; ++i)
    Vt[((long)bh * 128 + d0 + ty + 8*i) * 2048 + t0 + tx] = tile[tx][ty + 8*i];
}

// ---------------------------------------------------------------------------
// GEMM with XOR-octet-swizzled LDS. (unchanged from round 5)
// ---------------------------------------------------------------------------
template<typename OutT>
__global__ __launch_bounds__(256) void gemm_bt(
    const short* __restrict__ A,
    const short* __restrict__ B0, const short* __restrict__ B1, const short* __restrict__ B2,
    OutT* __restrict__ C0, OutT* __restrict__ C1, OutT* __restrict__ C2,
    int M, int N, int K)
{
  int z = blockIdx.z;
  const short* Bt = (z == 0) ? B0 : (z == 1) ? B1 : B2;
  OutT* C = (z == 0) ? C0 : (z == 1) ? C1 : C2;

  int m0 = blockIdx.y * 128, n0 = blockIdx.x * 128;
  int tid = threadIdx.x;
  int lane = tid & 63, w = tid >> 6;
  int quad = lane >> 4, l16 = lane & 15;
  int wm = w >> 1, wn = w & 1;

  __shared__ short As[128][64];
  __shared__ short Bs[128][64];

  f32x4 zero4 = {0.f, 0.f, 0.f, 0.f};
  f32x4 acc[4][4];
  #pragma unroll
  for (int i = 0; i < 4; ++i)
    #pragma unroll
    for (int j = 0; j < 4; ++j) acc[i][j] = zero4;

  int r8 = lane >> 3;
  int srow = w * 32 + r8;
  int scol = ((lane & 7) ^ r8) * 8;

  for (int k0 = 0; k0 < K; k0 += 64) {
    #pragma unroll
    for (int i = 0; i < 4; ++i) {
      ASYNC16(A  + (long)(m0 + srow + i*8) * K + k0 + scol, &As[w*32 + i*8][0]);
      ASYNC16(Bt + (long)(n0 + srow + i*8) * K + k0 + scol, &Bs[w*32 + i*8][0]);
    }
    __syncthreads();
    #pragma unroll
    for (int kt = 0; kt < 2; ++kt) {
      int po = ((kt*4 + quad) ^ (l16 & 7)) * 8;
      bf16x8 af[4], bfr[4];
      #pragma unroll
      for (int i = 0; i < 4; ++i)
        af[i] = *(const bf16x8*)&As[wm*64 + i*16 + l16][po];
      #pragma unroll
      for (int j = 0; j < 4; ++j)
        bfr[j] = *(const bf16x8*)&Bs[wn*64 + j*16 + l16][po];
      #pragma unroll
      for (int i = 0; i < 4; ++i)
        #pragma unroll
        for (int j = 0; j < 4; ++j)
          acc[i][j] = __builtin_amdgcn_mfma_f32_16x16x32_bf16(af[i], bfr[j], acc[i][j], 0, 0, 0);
    }
    __syncthreads();
  }

  #pragma unroll
  for (int i = 0; i < 4; ++i)
    #pragma unroll
    for (int j = 0; j < 4; ++j) {
      int row = m0 + wm*64 + i*16 + quad*4;
      int col = n0 + wn*64 + j*16 + l16;
      #pragma unroll
      for (int r = 0; r < 4; ++r) {
        float v = acc[i][j][r];
        if constexpr (sizeof(OutT) == 4)
          C[(long)(row + r) * N + col] = v;
        else
          C[(long)(row + r) * N + col] = (OutT)f2bf(v);
      }
    }
}

// ---------------------------------------------------------------------------
__global__ __launch_bounds__(256) void pointwise(
    const short* __restrict__ xb, const void* __restrict__ ve,
    const void* __restrict__ cosb, const void* __restrict__ sinb,
    const void* __restrict__ Wg, const int* __restrict__ flag,
    short* __restrict__ Qr, short* __restrict__ Kr, short* __restrict__ Vr)
{
  int row = blockIdx.x;
  int tid = threadIdx.x;
  int isbf = *flag;
  __shared__ float xg[32];
  __shared__ float gates[16];
  if (tid < 32) xg[tid] = bf2f(xb[(long)row * 2048 + tid]);
  __syncthreads();
  if (tid < 16) {
    float g = 0.f;
    #pragma unroll
    for (int i = 0; i < 32; ++i) g += xg[i] * ldf(Wg, i*16 + tid, isbf);
    gates[tid] = 2.0f / (1.0f + __expf(-g));
  }
  __syncthreads();
  #pragma unroll
  for (int it = 0; it < 8; ++it) {
    int idx = it * 256 + tid;
    int h = idx >> 7;
    long p = (long)row * 2048 + idx;
    Vr[p] = f2bf(bf2f(Vr[p]) + gates[h] * ldf(ve, p, isbf));
  }
  int lane = tid & 63, w = tid >> 6;
  int t = row & 2047;
  #pragma unroll
  for (int it = 0; it < 8; ++it) {
    int unit = it * 4 + w;
    short* P = (unit < 16) ? Qr : Kr;
    int h = unit & 15;
    long base = (long)row * 2048 + h * 128;
    float x1 = bf2f(P[base + lane]);
    float x2 = bf2f(P[base + lane + 64]);
    float c = ldf(cosb, t*64 + lane, isbf);
    float s = ldf(sinb, t*64 + lane, isbf);
    float r1 = x1 * c + x2 * s;
    float r2 = -x1 * s + x2 * c;
    float ss = r1*r1 + r2*r2;
    #pragma unroll
    for (int off = 32; off; off >>= 1) ss += __shfl_xor(ss, off);
    float rn = rsqrtf(ss * (1.0f/128.0f) + 1e-6f);
    P[base + lane]      = f2bf(r1 * rn);
    P[base + lane + 64] = f2bf(r2 * rn);
  }
}

// ---------------------------------------------------------------------------
// Flash v3: BQ=64, BK=64, fixed-max softmax (logits bounded by sqrt(128)
// since q,k are RMS-normalized), row-sums via ones-MFMA, double-buffered
// ASYNC16 staging, XOR-octet swizzle, paired q-tiles (bx, 31-bx).
// C1 = scale*log2(e), C2 = sqrt(128)*log2(e).
// ---------------------------------------------------------------------------
#define FL_C1 0.12751741f
#define FL_C2 16.321698f

__global__ __launch_bounds__(256) void flash(
    const short* __restrict__ Q, const short* __restrict__ K,
    const short* __restrict__ Vt, short* __restrict__ Y)
{
  int bx = blockIdx.x;
  int bh = blockIdx.y;
  int b = bh >> 4, h = bh & 15;
  int tid = threadIdx.x;
  int lane = tid & 63, w = tid >> 6;
  int quad = lane >> 4, l16 = lane & 15;

  __shared__ short Ks[2][64*128];    // [key][16 octets], phys = log ^ (key&7)
  __shared__ short Vts[2][128*64];   // [dim][8 octets],  phys = log ^ (dim&7)
  __shared__ short Ps[4][16*72];     // wave-private, padded stride 72

  int qtA = bx, qtB = 31 - bx;
  int nA = qtA + 1, nB = qtB + 1;
  int total = nA + nB;               // 34 for every block

  // staging lane constants (swizzle folded into global source octet)
  int kkey = tid >> 4;                         // + i*16
  int klo  = (tid & 15) ^ (kkey & 7);          // i*16 preserves key&7
  int vd   = tid >> 3;                         // + i*32
  int vlo  = (tid & 7) ^ (vd & 7);
  const short* Kbase = K + (long)(b*2048 + kkey) * 2048 + h*128 + klo*8;
  const short* Vbase = Vt + ((long)bh*128 + vd) * 2048 + vlo*8;

  f32x4 zero4 = {0.f, 0.f, 0.f, 0.f};
  f32x4 o[8];
  float l_i[4];
  bf16x8 qf[4];
  bf16x8 ones;
  #pragma unroll
  for (int j = 0; j < 8; ++j) ones[j] = (short)0x3F80;

  auto stage = [&](int tt, int buf) {
    int tl = (tt < nA) ? tt : tt - nA;
    long ko = (long)tl * 64 * 2048;
    int  vo = tl * 64;
    #pragma unroll
    for (int i = 0; i < 4; ++i)
      ASYNC16(Kbase + ko + (long)i*16*2048, &Ks[buf][(i*16 + w*4)*128]);
    #pragma unroll
    for (int i = 0; i < 4; ++i)
      ASYNC16(Vbase + vo + (long)i*32*2048, &Vts[buf][(i*32 + w*8)*64]);
  };
  auto loadQ = [&](int qt) {
    const short* Qb = Q + (long)(b*2048 + qt*64 + w*16 + l16) * 2048 + h*128;
    #pragma unroll
    for (int kt = 0; kt < 4; ++kt)
      qf[kt] = *(const bf16x8*)(Qb + kt*32 + quad*8);
  };
  auto flushO = [&](int qt) {
    #pragma unroll
    for (int r = 0; r < 4; ++r) {
      float inv = 1.0f / fmaxf(l_i[r], 1e-30f);
      short* yp = Y + (long)(b*2048 + qt*64 + w*16 + quad*4 + r) * 2048 + h*128;
      #pragma unroll
      for (int c8 = 0; c8 < 8; ++c8)
        yp[c8*16 + l16] = f2bf(o[c8][r] * inv);
    }
  };

  #pragma unroll
  for (int c = 0; c < 8; ++c) o[c] = zero4;
  #pragma unroll
  for (int r = 0; r < 4; ++r) l_i[r] = 0.f;
  loadQ(qtA);
  stage(0, 0);

  int qt = qtA, n_seg = nA, segbase = 0;
  for (int tt = 0; tt < total; ++tt) {
    int buf = tt & 1;
    asm volatile("s_waitcnt vmcnt(0)" ::: "memory");
    __builtin_amdgcn_s_barrier();
    if (tt + 1 < total) stage(tt + 1, buf ^ 1);
    if (tt == nA) {                       // segment switch A -> B
      flushO(qtA);
      loadQ(qtB);
      #pragma unroll
      for (int c = 0; c < 8; ++c) o[c] = zero4;
      #pragma unroll
      for (int r = 0; r < 4; ++r) l_i[r] = 0.f;
      qt = qtB; n_seg = nB; segbase = nA;
    }
    int tloc = tt - segbase;
    int kv0 = tloc * 64;

    // S = Q K^T  (16 q-rows x 64 keys per wave)
    f32x4 s[4];
    #pragma unroll
    for (int c = 0; c < 4; ++c) {
      f32x4 acc = zero4;
      #pragma unroll
      for (int kt = 0; kt < 4; ++kt) {
        int po = ((kt*4 + quad) ^ (l16 & 7)) * 8;
        bf16x8 kf = *(const bf16x8*)&Ks[buf][(c*16 + l16)*128 + po];
        acc = __builtin_amdgcn_mfma_f32_16x16x32_bf16(qf[kt], kf, acc, 0, 0, 0);
      }
      s[c] = acc;
    }

    // fixed-max softmax: p = 2^(s*C1 - C2); mask only on diagonal step
    bool domask = (tloc == n_seg - 1);
    int qgb = qt*64 + w*16 + quad*4;
    #pragma unroll
    for (int c = 0; c < 4; ++c) {
      int kg = kv0 + c*16 + l16;
      #pragma unroll
      for (int r = 0; r < 4; ++r) {
        float t = s[c][r] * FL_C1 - FL_C2;
        if (domask && kg > qgb + r) t = -1000.0f;
        float pv = exp2f(t);
        Ps[w][(quad*4 + r)*72 + c*16 + l16] = f2bf(pv);
      }
    }
    asm volatile("s_waitcnt lgkmcnt(0)" ::: "memory");
    bf16x8 pa0 = *(const bf16x8*)&Ps[w][l16*72 + quad*8];
    bf16x8 pa1 = *(const bf16x8*)&Ps[w][l16*72 + 32 + quad*8];

    // row-sums via ones-MFMA (C-layout aligns with l_i[r])
    f32x4 racc = __builtin_amdgcn_mfma_f32_16x16x32_bf16(pa0, ones, zero4, 0, 0, 0);
    racc = __builtin_amdgcn_mfma_f32_16x16x32_bf16(pa1, ones, racc, 0, 0, 0);
    #pragma unroll
    for (int r = 0; r < 4; ++r) l_i[r] += racc[r];

    // O += P V
    #pragma unroll
    for (int c8 = 0; c8 < 8; ++c8) {
      int po0 = ((0*4 + quad) ^ (l16 & 7)) * 8;
      int po1 = ((1*4 + quad) ^ (l16 & 7)) * 8;
      bf16x8 v0 = *(const bf16x8*)&Vts[buf][(c8*16 + l16)*64 + po0];
      bf16x8 v1 = *(const bf16x8*)&Vts[buf][(c8*16 + l16)*64 + po1];
      o[c8] = __builtin_amdgcn_mfma_f32_16x16x32_bf16(pa0, v0, o[c8], 0, 0, 0);
      o[c8] = __builtin_amdgcn_mfma_f32_16x16x32_bf16(pa1, v1, o[c8], 0, 0, 0);
    }
  }
  flushO(qtB);
}

// ---------------------------------------------------------------------------
extern "C" void kernel_launch(void* const* d_in, const int* in_sizes, int n_in,
                              void* d_out, int out_size, void* d_ws, size_t ws_size,
                              hipStream_t stream) {
  const void* x    = d_in[0];
  const void* ve   = d_in[1];
  const void* cosb = d_in[2];
  const void* sinb = d_in[3];
  const void* Wq   = d_in[4];
  const void* Wk   = d_in[5];
  const void* Wv   = d_in[6];
  const void* Wg   = d_in[7];
  const void* Wp   = d_in[8];
  float* out = (float*)d_out;   // reference output dtype: float32

  int*   flag = (int*)d_ws;
  short* base = (short*)d_ws + 256;
  short* wt0 = base;                       // 4M: Wq^T, then Wp^T
  short* wtk = base + 4194304L;            // 4M: Wk^T (dead after QKV gemm)
  short* wtv = base + 8388608L;            // 4M: Wv^T (dead after QKV gemm)
  short* Vt  = base + 4194304L;            // 8M: aliases wtk+wtv
  short* xb  = base + 12582912L;           // 8M: bf16 x (dead after pointwise)
  short* Y   = base + 12582912L;           // 8M: aliases xb
  short* Qr  = base + 20971520L;           // 8M
  short* Kr  = base + 29360128L;           // 8M
  short* Vr  = base + 37748736L;           // 8M

  detect_dtype<<<1, 64, 0, stream>>>((const short*)x, flag);
  convert_x<<<4096, 256, 0, stream>>>(x, xb, flag);
  transpose_w<<<dim3(64, 64, 3), dim3(32, 8), 0, stream>>>(Wq, wt0, Wk, wtk, Wv, wtv, flag);
  gemm_bt<short><<<dim3(16, 32, 3), 256, 0, stream>>>(xb, wt0, wtk, wtv, Qr, Kr, Vr, 4096, 2048, 2048);
  transpose_w<<<dim3(64, 64, 1), dim3(32, 8), 0, stream>>>(Wp, wt0, Wp, wt0, Wp, wt0, flag);
  pointwise<<<dim3(4096), 256, 0, stream>>>(xb, ve, cosb, sinb, Wg, flag, Qr, Kr, Vr);
  transpose_v<<<dim3(64, 4, 32), dim3(32, 8), 0, stream>>>(Vr, Vt);
  flash<<<dim3(16, 32), 256, 0, stream>>>(Qr, Kr, Vt, Y);
  gemm_bt<float><<<dim3(16, 32, 1), 256, 0, stream>>>(Y, wt0, wt0, wt0, out, out, out, 4096, 2048, 2048);
}